// Round 12
// baseline (148.313 us; speedup 1.0000x reference)
//
#include <hip/hip_runtime.h>
#include <hip/hip_bf16.h>

typedef __attribute__((ext_vector_type(8))) short short8;
typedef __attribute__((ext_vector_type(2))) float f32x2;
typedef __attribute__((ext_vector_type(4))) float f32x4;

__device__ __forceinline__ unsigned short f32_bf16(float f) {
  unsigned u = __float_as_uint(f);
  u += 0x7fffu + ((u >> 16) & 1u);  // round-to-nearest-even
  return (unsigned short)(u >> 16);
}

__device__ __forceinline__ short8 cvt8(float4 v0, float4 v1) {
  short8 f;
  f[0] = (short)f32_bf16(v0.x); f[1] = (short)f32_bf16(v0.y);
  f[2] = (short)f32_bf16(v0.z); f[3] = (short)f32_bf16(v0.w);
  f[4] = (short)f32_bf16(v1.x); f[5] = (short)f32_bf16(v1.y);
  f[6] = (short)f32_bf16(v1.z); f[7] = (short)f32_bf16(v1.w);
  return f;
}

// 4 fp8 (one dword of U, one of V) -> h1 = relu(U+V+b) -> two bf16-pair dwords
__device__ __forceinline__ void addrelu4(unsigned uw, unsigned vw, const float* b,
                                         unsigned& o0, unsigned& o1) {
  f32x2 ul = __builtin_amdgcn_cvt_pk_f32_fp8(uw, false);
  f32x2 uh = __builtin_amdgcn_cvt_pk_f32_fp8(uw, true);
  f32x2 vl = __builtin_amdgcn_cvt_pk_f32_fp8(vw, false);
  f32x2 vh = __builtin_amdgcn_cvt_pk_f32_fp8(vw, true);
  float s0 = ul[0] + vl[0] + b[0]; s0 = s0 > 0.f ? s0 : 0.f;
  float s1 = ul[1] + vl[1] + b[1]; s1 = s1 > 0.f ? s1 : 0.f;
  float s2 = uh[0] + vh[0] + b[2]; s2 = s2 > 0.f ? s2 : 0.f;
  float s3 = uh[1] + vh[1] + b[3]; s3 = s3 > 0.f ? s3 : 0.f;
  union { __hip_bfloat162 h; unsigned u; } p0, p1;
  p0.h = __float22bfloat162_rn(float2{s0, s1});
  p1.h = __float22bfloat162_rn(float2{s2, s3});
  o0 = p0.u; o1 = p1.u;
}

// DPP row_shr:N add — lane 15 of each 16-lane row ends with the row sum.
template <int CTRL>
__device__ __forceinline__ float dpp_add(float x) {
  int y = __builtin_amdgcn_update_dpp(0, __float_as_int(x), CTRL, 0xf, 0xf, true);
  return x + __int_as_float(y);
}
__device__ __forceinline__ float row_sum16(float x) {
  x = dpp_add<0x118>(x);
  x = dpp_add<0x114>(x);
  x = dpp_add<0x112>(x);
  x = dpp_add<0x111>(x);
  return x;
}

// ---- pass 1: UV[n] = [ Z[n]·W1a , Z[n]·W1b ] in fp8 e4m3 (128 B per node) --
// (unchanged from R11 — verified)
__global__ __launch_bounds__(256, 2) void uv_kernel(
    const float* __restrict__ z, const float* __restrict__ W1,
    unsigned char* __restrict__ uv, int nNodes) {
  __shared__ unsigned short w1l[32 * 64 * 8];  // 32 KB
  const int tid = threadIdx.x;
  const int wv  = tid >> 6;
  const int l   = tid & 63;
  const int l15 = l & 15;
  const int q   = l >> 4;

#pragma unroll
  for (int pp = 0; pp < 8; ++pp) {
    int p = wv * 8 + pp;       // p = c*8 + t
    int c = p >> 3, t = p & 7;
    short8 f;
#pragma unroll
    for (int j = 0; j < 8; ++j) {
      int k = c * 32 + q * 8 + j;
      int n = l15 * 8 + t;
      int row = (n < 64) ? k : (k + 128);
      f[j] = (short)f32_bf16(W1[row * 64 + (n & 63)]);
    }
    *(short8*)(w1l + (p * 64 + l) * 8) = f;
  }
  __syncthreads();

  const int nTiles = (nNodes + 15) >> 4;
  const int stride = gridDim.x * 4;
  for (int tile = blockIdx.x * 4 + wv; tile < nTiles; tile += stride) {
    int node = tile * 16 + l15;
    node = node < nNodes ? node : nNodes - 1;
    const float* zr = z + (size_t)node * 128;
    short8 a[4];
#pragma unroll
    for (int c = 0; c < 4; ++c) {
      int off = c * 32 + q * 8;
      a[c] = cvt8(*(const float4*)(zr + off), *(const float4*)(zr + off + 4));
    }
    f32x4 acc[8];
#pragma unroll
    for (int t = 0; t < 8; ++t) { acc[t][0] = 0.f; acc[t][1] = 0.f; acc[t][2] = 0.f; acc[t][3] = 0.f; }
#pragma unroll
    for (int c = 0; c < 4; ++c)
#pragma unroll
      for (int t = 0; t < 8; ++t) {
        short8 wf = *(const short8*)(w1l + ((c * 8 + t) * 64 + l) * 8);
        acc[t] = __builtin_amdgcn_mfma_f32_16x16x32_bf16(a[c], wf, acc[t], 0, 0, 0);
      }
#pragma unroll
    for (int r = 0; r < 4; ++r) {
      int no = tile * 16 + q * 4 + r;
      if (no < nNodes) {
        unsigned d0 = __builtin_amdgcn_cvt_pk_fp8_f32(acc[0][r], acc[1][r], 0, false);
        d0 = __builtin_amdgcn_cvt_pk_fp8_f32(acc[2][r], acc[3][r], d0, true);
        unsigned d1 = __builtin_amdgcn_cvt_pk_fp8_f32(acc[4][r], acc[5][r], 0, false);
        d1 = __builtin_amdgcn_cvt_pk_fp8_f32(acc[6][r], acc[7][r], d1, true);
        uint2 st; st.x = d0; st.y = d1;
        *(uint2*)(uv + (size_t)no * 128 + l15 * 8) = st;
      }
    }
  }
}

// ---- pass 2: 64 edges per wave-iteration (4 groups of 16) -------------------
// R9-vs-R11 disambiguation: equal wall time at half the miss bytes => the
// gather is LATENCY-bound (Little's law), not byte-throughput-bound. Fix:
// 4x the outstanding bytes per wave — all 16 UV uint2 loads (4 groups) issue
// back-to-back before any consumption; vmcnt in-order semantics let group g
// wait only on its own 4 loads. ~100 arch regs, under the measured 128 wall.
__global__ __launch_bounds__(256, 2) void lp_edge(
    const unsigned char* __restrict__ uv, const int* __restrict__ ei,
    const float* __restrict__ b1,
    const float* __restrict__ W2, const float* __restrict__ b2,
    const float* __restrict__ W3, const float* __restrict__ b3,
    float* __restrict__ out, int nEdges) {
  const int tid = threadIdx.x;
  const int wv  = tid >> 6;
  const int l   = tid & 63;
  const int l15 = l & 15;
  const int q   = l >> 4;

  short8 w2f[2][2];
#pragma unroll
  for (int c = 0; c < 2; ++c)
#pragma unroll
    for (int t = 0; t < 2; ++t) {
      short8 f;
#pragma unroll
      for (int j = 0; j < 8; ++j)
        f[j] = (short)f32_bf16(W2[(c * 32 + q * 8 + j) * 32 + (t * 16 + l15)]);
      w2f[c][t] = f;
    }
  float bb2[2];
#pragma unroll
  for (int t = 0; t < 2; ++t) bb2[t] = b2[t * 16 + l15];
  const float w3a = W3[l15], w3b = W3[16 + l15], b3v = b3[0];
  float b1f0[8], b1f1[8];
#pragma unroll
  for (int j = 0; j < 8; ++j) { b1f0[j] = b1[q * 8 + j]; b1f1[j] = b1[32 + q * 8 + j]; }

  const int nIter = (nEdges + 63) >> 6;   // 64 edges per iteration
  const int stride = gridDim.x * 4;
  int iter = blockIdx.x * 4 + wv;

  int cS[4], cD[4];
  if (iter < nIter) {
#pragma unroll
    for (int g = 0; g < 4; ++g) {
      int e = iter * 64 + g * 16 + l15;
      e = e < nEdges ? e : nEdges - 1;
      cS[g] = ei[e];
      cD[g] = ei[nEdges + e];
    }
  }

  for (; iter < nIter; iter += stride) {
    // ---- all 16 UV loads issue before any consumption ----
    uint2 u0[4], u1[4], v0[4], v1[4];
#pragma unroll
    for (int g = 0; g < 4; ++g) {
      const unsigned char* us = uv + (size_t)cS[g] * 128;       // U: bytes 0..63
      const unsigned char* vd = uv + (size_t)cD[g] * 128 + 64;  // V: bytes 64..127
      u0[g] = *(const uint2*)(us + q * 8);
      u1[g] = *(const uint2*)(us + 32 + q * 8);
      v0[g] = *(const uint2*)(vd + q * 8);
      v1[g] = *(const uint2*)(vd + 32 + q * 8);
    }

    // ---- prefetch next iteration's edge indices ----
    int nit = iter + stride;
    if (nit < nIter) {
#pragma unroll
      for (int g = 0; g < 4; ++g) {
        int e = nit * 64 + g * 16 + l15;
        e = e < nEdges ? e : nEdges - 1;
        cS[g] = ei[e];
        cD[g] = ei[nEdges + e];
      }
    }

    // ---- per group: decode+relu -> layer2 MFMA -> layer3 DPP -> store ----
#pragma unroll
    for (int g = 0; g < 4; ++g) {
      union { unsigned u[4]; short8 s; } f0, f1;
      addrelu4(u0[g].x, v0[g].x, &b1f0[0], f0.u[0], f0.u[1]);
      addrelu4(u0[g].y, v0[g].y, &b1f0[4], f0.u[2], f0.u[3]);
      addrelu4(u1[g].x, v1[g].x, &b1f1[0], f1.u[0], f1.u[1]);
      addrelu4(u1[g].y, v1[g].y, &b1f1[4], f1.u[2], f1.u[3]);

      f32x4 acc2[2];
#pragma unroll
      for (int t = 0; t < 2; ++t) {
        acc2[t][0] = bb2[t]; acc2[t][1] = bb2[t]; acc2[t][2] = bb2[t]; acc2[t][3] = bb2[t];
      }
#pragma unroll
      for (int t = 0; t < 2; ++t) {
        acc2[t] = __builtin_amdgcn_mfma_f32_16x16x32_bf16(f0.s, w2f[0][t], acc2[t], 0, 0, 0);
        acc2[t] = __builtin_amdgcn_mfma_f32_16x16x32_bf16(f1.s, w2f[1][t], acc2[t], 0, 0, 0);
      }

      float p[4];
#pragma unroll
      for (int r = 0; r < 4; ++r) {
        float h0 = acc2[0][r]; h0 = h0 > 0.f ? h0 : 0.f;
        float h1v = acc2[1][r]; h1v = h1v > 0.f ? h1v : 0.f;
        p[r] = row_sum16(h0 * w3a + h1v * w3b);
      }

      if (l15 == 15) {
        int eb = iter * 64 + g * 16 + q * 4;
        float4 o;
        o.x = 1.f / (1.f + __expf(-(p[0] + b3v)));
        o.y = 1.f / (1.f + __expf(-(p[1] + b3v)));
        o.z = 1.f / (1.f + __expf(-(p[2] + b3v)));
        o.w = 1.f / (1.f + __expf(-(p[3] + b3v)));
        if (eb + 3 < nEdges) {
          *(float4*)(out + eb) = o;
        } else {
          if (eb < nEdges)     out[eb]     = o.x;
          if (eb + 1 < nEdges) out[eb + 1] = o.y;
          if (eb + 2 < nEdges) out[eb + 2] = o.z;
        }
      }
    }
  }
}

// ---- correctness-only fallback (ws too small; never expected) ---------------
__global__ void lp_naive(const float* __restrict__ z, const int* __restrict__ ei,
                         const float* __restrict__ W1, const float* __restrict__ b1,
                         const float* __restrict__ W2, const float* __restrict__ b2,
                         const float* __restrict__ W3, const float* __restrict__ b3,
                         float* __restrict__ out, int nEdges) {
  int e = blockIdx.x * 256 + threadIdx.x;
  if (e >= nEdges) return;
  int s = ei[e], d = ei[nEdges + e];
  float h1[64], h2[32];
  for (int k = 0; k < 64; ++k) {
    float a = b1[k];
    for (int i = 0; i < 128; ++i) a += z[(size_t)s * 128 + i] * W1[i * 64 + k];
    for (int i = 0; i < 128; ++i) a += z[(size_t)d * 128 + i] * W1[(128 + i) * 64 + k];
    h1[k] = a > 0.f ? a : 0.f;
  }
  for (int k = 0; k < 32; ++k) {
    float a = b2[k];
    for (int i = 0; i < 64; ++i) a += h1[i] * W2[i * 32 + k];
    h2[k] = a > 0.f ? a : 0.f;
  }
  float lg = b3[0];
  for (int i = 0; i < 32; ++i) lg += h2[i] * W3[i];
  out[e] = 1.f / (1.f + __expf(-lg));
}

extern "C" void kernel_launch(void* const* d_in, const int* in_sizes, int n_in,
                              void* d_out, int out_size, void* d_ws, size_t ws_size,
                              hipStream_t stream) {
  const float* z  = (const float*)d_in[0];
  const int* ei   = (const int*)d_in[1];
  const float* W1 = (const float*)d_in[2];
  const float* b1 = (const float*)d_in[3];
  const float* W2 = (const float*)d_in[4];
  const float* b2 = (const float*)d_in[5];
  const float* W3 = (const float*)d_in[6];
  const float* b3 = (const float*)d_in[7];
  float* out = (float*)d_out;

  const int nZ = in_sizes[0];
  const int nNodes = nZ / 128;
  const int nEdges = in_sizes[1] / 2;

  if (ws_size >= (size_t)nNodes * 128) {
    unsigned char* uvp = (unsigned char*)d_ws;
    uv_kernel<<<1568, 256, 0, stream>>>(z, W1, uvp, nNodes);
    lp_edge<<<4096, 256, 0, stream>>>(uvp, ei, b1, W2, b2, W3, b3, out, nEdges);
  } else {
    lp_naive<<<(nEdges + 255) / 256, 256, 0, stream>>>(z, ei, W1, b1, W2, b2, W3, b3, out, nEdges);
  }
}